// Round 1
// baseline (1467.631 us; speedup 1.0000x reference)
//
#include <hip/hip_runtime.h>
#include <math.h>

#define CH 128          // HID
#define F2 256          // HEADS*CH
#define NG 64           // graphs

// ---------------- GEMM: C[M,Nn] = act(A[M,K] @ W[Nn,K]^T + bias) ----------------
// A row-major [M,K], W row-major [N,K] (PyTorch linear weight layout), both K-contig.
template<int ACT>
__global__ __launch_bounds__(256) void gemm_nt(
    const float* __restrict__ A, const float* __restrict__ W,
    const float* __restrict__ bias, float* __restrict__ C,
    int M, int Nn, int K) {
  // 64x64 tile, BK=16, 256 threads, 4x4 per thread. LDS stored transposed [k][m].
  __shared__ float As[16][68];
  __shared__ float Ws[16][68];
  const int tid = threadIdx.x;
  const int tx = tid & 15, ty = tid >> 4;
  const int bm = blockIdx.x * 64, bn = blockIdx.y * 64;
  const int lr = tid >> 2, lc = (tid & 3) * 4;
  const bool arow_ok = (bm + lr) < M;
  const bool wrow_ok = (bn + lr) < Nn;
  const float* aptr = A + (size_t)(bm + lr) * K;
  const float* wptr = W + (size_t)(bn + lr) * K;
  float acc[4][4] = {};
  for (int k0 = 0; k0 < K; k0 += 16) {
    float4 av = make_float4(0.f, 0.f, 0.f, 0.f);
    float4 wv = make_float4(0.f, 0.f, 0.f, 0.f);
    if (arow_ok) av = *(const float4*)(aptr + k0 + lc);
    if (wrow_ok) wv = *(const float4*)(wptr + k0 + lc);
    __syncthreads();            // previous iteration's reads complete
    As[lc + 0][lr] = av.x; As[lc + 1][lr] = av.y; As[lc + 2][lr] = av.z; As[lc + 3][lr] = av.w;
    Ws[lc + 0][lr] = wv.x; Ws[lc + 1][lr] = wv.y; Ws[lc + 2][lr] = wv.z; Ws[lc + 3][lr] = wv.w;
    __syncthreads();
#pragma unroll
    for (int kk = 0; kk < 16; ++kk) {
      const float4 a = *(const float4*)&As[kk][ty * 4];
      const float4 b = *(const float4*)&Ws[kk][tx * 4];
      acc[0][0] += a.x * b.x; acc[0][1] += a.x * b.y; acc[0][2] += a.x * b.z; acc[0][3] += a.x * b.w;
      acc[1][0] += a.y * b.x; acc[1][1] += a.y * b.y; acc[1][2] += a.y * b.z; acc[1][3] += a.y * b.w;
      acc[2][0] += a.z * b.x; acc[2][1] += a.z * b.y; acc[2][2] += a.z * b.z; acc[2][3] += a.z * b.w;
      acc[3][0] += a.w * b.x; acc[3][1] += a.w * b.y; acc[3][2] += a.w * b.z; acc[3][3] += a.w * b.w;
    }
  }
#pragma unroll
  for (int i = 0; i < 4; ++i) {
    int row = bm + ty * 4 + i;
    if (row >= M) continue;
#pragma unroll
    for (int j = 0; j < 4; ++j) {
      int col = bn + tx * 4 + j;
      if (col >= Nn) continue;
      float v = acc[i][j] + bias[col];
      if (ACT) v = fmaxf(v, 0.f);
      C[(size_t)row * Nn + col] = v;
    }
  }
}

// ---------------- CSR build ----------------
__global__ void fill_zero_i32(int* __restrict__ p, int n) {
  int i = blockIdx.x * blockDim.x + threadIdx.x;
  if (i < n) p[i] = 0;
}
__global__ void copy_i32(const int* __restrict__ a, int* __restrict__ b, int n) {
  int i = blockIdx.x * blockDim.x + threadIdx.x;
  if (i < n) b[i] = a[i];
}
__global__ void edge_hist(const int* __restrict__ ei, int E, int Etot, int* __restrict__ counts) {
  int e = blockIdx.x * blockDim.x + threadIdx.x;
  if (e >= Etot) return;
  int d = (e < E) ? ei[E + e] : (e - E);
  atomicAdd(&counts[d], 1);
}
__global__ __launch_bounds__(1024) void scan_excl(const int* __restrict__ counts,
                                                  int* __restrict__ indptr, int n) {
  __shared__ int sm[1024];
  const int tid = threadIdx.x;
  const int chunk = (n + 1023) >> 10;
  const int s = tid * chunk;
  const int e = min(s + chunk, n);
  int loc = 0;
  for (int i = s; i < e; ++i) loc += counts[i];
  sm[tid] = loc;
  __syncthreads();
  for (int off = 1; off < 1024; off <<= 1) {
    int v = (tid >= off) ? sm[tid - off] : 0;
    __syncthreads();
    sm[tid] += v;
    __syncthreads();
  }
  int pre = (tid == 0) ? 0 : sm[tid - 1];
  for (int i = s; i < e; ++i) { indptr[i] = pre; pre += counts[i]; }
  if (tid == 1023) indptr[n] = sm[1023];
}
__global__ void edge_scatter(const int* __restrict__ ei, int E, int Etot,
                             int* __restrict__ cur, int* __restrict__ csr_src,
                             int* __restrict__ csr_eid) {
  int e = blockIdx.x * blockDim.x + threadIdx.x;
  if (e >= Etot) return;
  int s, d;
  if (e < E) { s = ei[e]; d = ei[E + e]; } else { s = e - E; d = s; }
  int p = atomicAdd(&cur[d], 1);
  csr_src[p] = s;
  csr_eid[p] = e;
}

// ---------------- edge attention scores: one wave per edge ----------------
__global__ __launch_bounds__(256) void edge_scores(
    const int* __restrict__ ei, int E, int Etot,
    const float* __restrict__ XL, const float* __restrict__ XR,
    const float* __restrict__ att, float* __restrict__ ES) {
  int e = (int)((blockIdx.x * (size_t)256 + threadIdx.x) >> 6);
  if (e >= Etot) return;
  const int lane = threadIdx.x & 63;
  int src, dst;
  if (e < E) { src = ei[e]; dst = ei[E + e]; } else { src = e - E; dst = src; }
  const int f = lane * 4;   // flat [h*128+c] channel
  const float4 a = *(const float4*)(XL + (size_t)src * F2 + f);
  const float4 b = *(const float4*)(XR + (size_t)dst * F2 + f);
  const float4 t = *(const float4*)(att + f);
  float p = 0.f;
  { float v = a.x + b.x; v = v > 0.f ? v : 0.2f * v; p += v * t.x; }
  { float v = a.y + b.y; v = v > 0.f ? v : 0.2f * v; p += v * t.y; }
  { float v = a.z + b.z; v = v > 0.f ? v : 0.2f * v; p += v * t.z; }
  { float v = a.w + b.w; v = v > 0.f ? v : 0.2f * v; p += v * t.w; }
  // reduce within each 32-lane half (head0 = lanes 0..31, head1 = 32..63)
  p += __shfl_xor(p, 1);
  p += __shfl_xor(p, 2);
  p += __shfl_xor(p, 4);
  p += __shfl_xor(p, 8);
  p += __shfl_xor(p, 16);
  if (lane == 0)       ES[(size_t)e * 2]     = p;
  else if (lane == 32) ES[(size_t)e * 2 + 1] = p;
}

// ---------------- per-node softmax + aggregate: one wave per node ----------------
__global__ __launch_bounds__(256) void node_agg(
    const float* __restrict__ ES, const int* __restrict__ indptr,
    const int* __restrict__ csr_src, const int* __restrict__ csr_eid,
    const float* __restrict__ XL, const float* __restrict__ bias,
    float* __restrict__ OUT, int N) {
  int node = (int)((blockIdx.x * (size_t)256 + threadIdx.x) >> 6);
  if (node >= N) return;
  const int lane = threadIdx.x & 63;
  const int s = indptr[node], e = indptr[node + 1];
  // pass 1: per-head max (exact, matches segment_max)
  float m0 = -3.4e38f, m1 = -3.4e38f;
  for (int k = s; k < e; ++k) {
    int eid = csr_eid[k];
    m0 = fmaxf(m0, ES[(size_t)eid * 2]);
    m1 = fmaxf(m1, ES[(size_t)eid * 2 + 1]);
  }
  // pass 2: denominators
  float d0 = 0.f, d1 = 0.f;
  for (int k = s; k < e; ++k) {
    int eid = csr_eid[k];
    d0 += expf(ES[(size_t)eid * 2] - m0);
    d1 += expf(ES[(size_t)eid * 2 + 1] - m1);
  }
  const int h = lane >> 5;
  const float mh = h ? m1 : m0;
  const float dh = h ? d1 : d0;
  const int f = lane * 4;
  float a0 = 0.f, a1 = 0.f, a2 = 0.f, a3 = 0.f;
  for (int k = s; k < e; ++k) {
    int eid = csr_eid[k];
    int sn = csr_src[k];
    float wgt = expf(ES[(size_t)eid * 2 + h] - mh);
    const float4 x = *(const float4*)(XL + (size_t)sn * F2 + f);
    a0 += wgt * x.x; a1 += wgt * x.y; a2 += wgt * x.z; a3 += wgt * x.w;
  }
  const float inv = 1.f / (dh + 1e-16f);
  a0 *= inv; a1 *= inv; a2 *= inv; a3 *= inv;
  // mean over heads: lane l (head0, chans f..f+3) pairs with lane l+32 (head1)
  float o0 = 0.5f * (a0 + __shfl_xor(a0, 32));
  float o1 = 0.5f * (a1 + __shfl_xor(a1, 32));
  float o2 = 0.5f * (a2 + __shfl_xor(a2, 32));
  float o3 = 0.5f * (a3 + __shfl_xor(a3, 32));
  if (lane < 32) {
    float4 r;
    r.x = fmaxf(o0 + bias[f + 0], 0.f);
    r.y = fmaxf(o1 + bias[f + 1], 0.f);
    r.z = fmaxf(o2 + bias[f + 2], 0.f);
    r.w = fmaxf(o3 + bias[f + 3], 0.f);
    *(float4*)(OUT + (size_t)node * CH + f) = r;
  }
}

// ---------------- gate scalar: one wave per node ----------------
__global__ __launch_bounds__(256) void gate_dot(
    const float* __restrict__ T, const float* __restrict__ w2,
    const float* __restrict__ b2, float* __restrict__ gate, int N) {
  int node = (int)((blockIdx.x * (size_t)256 + threadIdx.x) >> 6);
  if (node >= N) return;
  const int lane = threadIdx.x & 63;
  const float* tr = T + (size_t)node * CH;
  float p = tr[lane] * w2[lane] + tr[lane + 64] * w2[lane + 64];
  p += __shfl_xor(p, 1);
  p += __shfl_xor(p, 2);
  p += __shfl_xor(p, 4);
  p += __shfl_xor(p, 8);
  p += __shfl_xor(p, 16);
  p += __shfl_xor(p, 32);
  if (lane == 0) gate[node] = p + b2[0];
}

// ---------------- per-graph softmax pooling: one block per graph ----------------
__global__ __launch_bounds__(128) void pool_kernel(
    const float* __restrict__ gate, const int* __restrict__ batch,
    const float* __restrict__ H, float* __restrict__ Gout, int N) {
  const int g = blockIdx.x, tid = threadIdx.x;
  int lo = 0, hi = N;
  while (lo < hi) { int mid = (lo + hi) >> 1; if (batch[mid] < g) lo = mid + 1; else hi = mid; }
  const int s = lo;
  lo = 0; hi = N;
  while (lo < hi) { int mid = (lo + hi) >> 1; if (batch[mid] < g + 1) lo = mid + 1; else hi = mid; }
  const int e = lo;
  if (s >= e) { Gout[(size_t)g * CH + tid] = 0.f; return; }
  __shared__ float red[128];
  float m = -3.4e38f;
  for (int n = s + tid; n < e; n += 128) m = fmaxf(m, gate[n]);
  red[tid] = m; __syncthreads();
  for (int off = 64; off; off >>= 1) {
    if (tid < off) red[tid] = fmaxf(red[tid], red[tid + off]);
    __syncthreads();
  }
  m = red[0]; __syncthreads();
  float d = 0.f;
  for (int n = s + tid; n < e; n += 128) d += expf(gate[n] - m);
  red[tid] = d; __syncthreads();
  for (int off = 64; off; off >>= 1) {
    if (tid < off) red[tid] += red[tid + off];
    __syncthreads();
  }
  d = red[0];
  float acc = 0.f;
  for (int n = s; n < e; ++n) acc += expf(gate[n] - m) * H[(size_t)n * CH + tid];
  Gout[(size_t)g * CH + tid] = acc / (d + 1e-16f);
}

// ---------------- head MLP + normalize: one block per graph ----------------
__global__ __launch_bounds__(128) void head_kernel(
    const float* __restrict__ Gin, const float* __restrict__ w1, const float* __restrict__ b1,
    const float* __restrict__ w2, const float* __restrict__ b2, float* __restrict__ out) {
  const int g = blockIdx.x, tid = threadIdx.x;
  __shared__ float gs[128], ts[128], o[2];
  gs[tid] = Gin[(size_t)g * CH + tid];
  __syncthreads();
  float a = b1[tid];
  for (int k = 0; k < CH; ++k) a += w1[tid * CH + k] * gs[k];
  ts[tid] = fmaxf(a, 0.f);
  __syncthreads();
  if (tid < 2) {
    float v = b2[tid];
    for (int d2 = 0; d2 < CH; ++d2) v += w2[tid * CH + d2] * ts[d2];
    o[tid] = v;
  }
  __syncthreads();
  if (tid == 0) {
    float nrm = sqrtf(o[0] * o[0] + o[1] * o[1]);
    nrm = fmaxf(nrm, 1e-12f);
    out[g * 2 + 0] = o[0] / nrm;
    out[g * 2 + 1] = o[1] / nrm;
  }
}

extern "C" void kernel_launch(void* const* d_in, const int* in_sizes, int n_in,
                              void* d_out, int out_size, void* d_ws, size_t ws_size,
                              hipStream_t stream) {
  const float* x       = (const float*)d_in[0];
  const int*   ei      = (const int*)d_in[1];
  const int*   batch   = (const int*)d_in[2];
  const float* enc_w1  = (const float*)d_in[3];
  const float* enc_b1  = (const float*)d_in[4];
  const float* enc_w2  = (const float*)d_in[5];
  const float* enc_b2  = (const float*)d_in[6];
  const float* c1_wl   = (const float*)d_in[7];
  const float* c1_bl   = (const float*)d_in[8];
  const float* c1_wr   = (const float*)d_in[9];
  const float* c1_br   = (const float*)d_in[10];
  const float* c1_att  = (const float*)d_in[11];
  const float* c1_bias = (const float*)d_in[12];
  const float* c2_wl   = (const float*)d_in[13];
  const float* c2_bl   = (const float*)d_in[14];
  const float* c2_wr   = (const float*)d_in[15];
  const float* c2_br   = (const float*)d_in[16];
  const float* c2_att  = (const float*)d_in[17];
  const float* c2_bias = (const float*)d_in[18];
  const float* gate_w1 = (const float*)d_in[19];
  const float* gate_b1 = (const float*)d_in[20];
  const float* gate_w2 = (const float*)d_in[21];
  const float* gate_b2 = (const float*)d_in[22];
  const float* head_w1 = (const float*)d_in[23];
  const float* head_b1 = (const float*)d_in[24];
  const float* head_w2 = (const float*)d_in[25];
  const float* head_b2 = (const float*)d_in[26];

  const int N    = in_sizes[2];
  const int E    = in_sizes[1] / 2;
  const int INF_ = in_sizes[0] / N;   // input feature dim (256)
  const int Etot = E + N;

  char* wp = (char*)d_ws;
  auto alloc = [&](size_t bytes) -> void* {
    void* p = (void*)wp;
    wp += (bytes + 255) & ~(size_t)255;
    return p;
  };
  float* XL      = (float*)alloc((size_t)N * F2 * 4);
  float* XR      = (float*)alloc((size_t)N * F2 * 4);
  float* H0      = (float*)alloc((size_t)N * CH * 4);
  float* H1      = (float*)alloc((size_t)N * CH * 4);
  float* ES      = (float*)alloc((size_t)Etot * 2 * 4);
  int*   counts  = (int*)alloc((size_t)N * 4);
  int*   indptr  = (int*)alloc((size_t)(N + 1) * 4);
  int*   cur     = (int*)alloc((size_t)N * 4);
  int*   csr_src = (int*)alloc((size_t)Etot * 4);
  int*   csr_eid = (int*)alloc((size_t)Etot * 4);
  float* gateb   = (float*)alloc((size_t)N * 4);
  float* GS      = (float*)alloc((size_t)NG * CH * 4);

  const dim3 blk(256);
  const int gM = (N + 63) / 64;

  // encoder
  gemm_nt<1><<<dim3(gM, CH / 64), blk, 0, stream>>>(x, enc_w1, enc_b1, H0, N, CH, INF_);
  gemm_nt<1><<<dim3(gM, CH / 64), blk, 0, stream>>>(H0, enc_w2, enc_b2, H1, N, CH, CH);

  // CSR by dst (shared by both convs)
  fill_zero_i32<<<(N + 255) / 256, blk, 0, stream>>>(counts, N);
  edge_hist<<<(Etot + 255) / 256, blk, 0, stream>>>(ei, E, Etot, counts);
  scan_excl<<<1, 1024, 0, stream>>>(counts, indptr, N);
  copy_i32<<<(N + 255) / 256, blk, 0, stream>>>(indptr, cur, N);
  edge_scatter<<<(Etot + 255) / 256, blk, 0, stream>>>(ei, E, Etot, cur, csr_src, csr_eid);

  // conv1
  gemm_nt<0><<<dim3(gM, F2 / 64), blk, 0, stream>>>(H1, c1_wl, c1_bl, XL, N, F2, CH);
  gemm_nt<0><<<dim3(gM, F2 / 64), blk, 0, stream>>>(H1, c1_wr, c1_br, XR, N, F2, CH);
  edge_scores<<<(Etot + 3) / 4, blk, 0, stream>>>(ei, E, Etot, XL, XR, c1_att, ES);
  node_agg<<<(N + 3) / 4, blk, 0, stream>>>(ES, indptr, csr_src, csr_eid, XL, c1_bias, H0, N);

  // conv2
  gemm_nt<0><<<dim3(gM, F2 / 64), blk, 0, stream>>>(H0, c2_wl, c2_bl, XL, N, F2, CH);
  gemm_nt<0><<<dim3(gM, F2 / 64), blk, 0, stream>>>(H0, c2_wr, c2_br, XR, N, F2, CH);
  edge_scores<<<(Etot + 3) / 4, blk, 0, stream>>>(ei, E, Etot, XL, XR, c2_att, ES);
  node_agg<<<(N + 3) / 4, blk, 0, stream>>>(ES, indptr, csr_src, csr_eid, XL, c2_bias, H1, N);

  // gate MLP (t = relu(h3 @ gw1^T + gb1) into XL scratch), then scalar gate
  gemm_nt<1><<<dim3(gM, CH / 64), blk, 0, stream>>>(H1, gate_w1, gate_b1, XL, N, CH, CH);
  gate_dot<<<(N + 3) / 4, blk, 0, stream>>>(XL, gate_w2, gate_b2, gateb, N);

  // per-graph softmax pooling over sorted batch
  pool_kernel<<<NG, 128, 0, stream>>>(gateb, batch, H1, GS, N);

  // head + normalize
  head_kernel<<<NG, 128, 0, stream>>>(GS, head_w1, head_b1, head_w2, head_b2, (float*)d_out);
}

// Round 2
// 1334.913 us; speedup vs baseline: 1.0994x; 1.0994x over previous
//
#include <hip/hip_runtime.h>
#include <math.h>

#define CH 128          // HID
#define F2 256          // HEADS*CH
#define NG 64           // graphs

typedef __attribute__((ext_vector_type(8))) short short8;
typedef __attribute__((ext_vector_type(4))) float f32x4;

__device__ inline ushort f2bf(float x) {
  uint u = __float_as_uint(x);
  return (ushort)((u + 0x7fffu + ((u >> 16) & 1u)) >> 16);
}
__device__ inline float bf2f(ushort h) { return __uint_as_float(((uint)h) << 16); }

// ---------------- split-bf16 MFMA GEMM: C[M,Nn] = act(A[M,K] @ W[Nn,K]^T + bias) ----
// A row-major [M,K] fp32, W row-major [Nn,K] fp32. Each fp32 -> hi+lo bf16;
// C = Ah.Bh + Ah.Bl + Al.Bh (drop Al.Bl, ~2^-16 rel err). Nn%64==0, K%32==0.
template<int ACT>
__global__ __launch_bounds__(256) void gemm_nt_mfma(
    const float* __restrict__ A, const float* __restrict__ W,
    const float* __restrict__ bias, float* __restrict__ C,
    int M, int Nn, int K) {
  // tile 128(M) x 64(N), BK=32. LDS rows padded to 40 bf16 (80B) -> b128 conflict-free.
  __shared__ ushort Ah[128 * 40], Al[128 * 40], Wh[64 * 40], Wl[64 * 40];
  const int tid = threadIdx.x;
  const int lane = tid & 63;
  const int wid = tid >> 6;
  const int wm = wid >> 1, wn = wid & 1;          // 2x2 waves, each 64x32
  const int bm = blockIdx.x * 128, bn = blockIdx.y * 64;
  const int fr = lane & 15, fg = lane >> 4;

  f32x4 acc[4][2];
#pragma unroll
  for (int i = 0; i < 4; ++i)
#pragma unroll
    for (int j = 0; j < 2; ++j) acc[i][j] = (f32x4)0.f;

  for (int k0 = 0; k0 < K; k0 += 32) {
    // ---- global loads (fp32) ----
    float4 av[4], wv[2];
#pragma unroll
    for (int i = 0; i < 4; ++i) {
      const int c = tid + 256 * i;          // 1024 float4 chunks: 128 rows x 8
      const int row = c >> 3, kq = c & 7;
      const int gr = bm + row;
      av[i] = (gr < M) ? *(const float4*)(A + (size_t)gr * K + k0 + kq * 4)
                       : make_float4(0.f, 0.f, 0.f, 0.f);
    }
#pragma unroll
    for (int i = 0; i < 2; ++i) {
      const int c = tid + 256 * i;          // 512 chunks: 64 rows x 8
      const int row = c >> 3, kq = c & 7;
      wv[i] = *(const float4*)(W + (size_t)(bn + row) * K + k0 + kq * 4);
    }
    __syncthreads();                        // previous iteration's LDS reads done
    // ---- convert + LDS write ----
#pragma unroll
    for (int i = 0; i < 4; ++i) {
      const int c = tid + 256 * i;
      const int row = c >> 3, kq = c & 7;
      const float4 v = av[i];
      ushort4 h, l;
      h.x = f2bf(v.x); l.x = f2bf(v.x - bf2f(h.x));
      h.y = f2bf(v.y); l.y = f2bf(v.y - bf2f(h.y));
      h.z = f2bf(v.z); l.z = f2bf(v.z - bf2f(h.z));
      h.w = f2bf(v.w); l.w = f2bf(v.w - bf2f(h.w));
      *(ushort4*)&Ah[row * 40 + kq * 4] = h;
      *(ushort4*)&Al[row * 40 + kq * 4] = l;
    }
#pragma unroll
    for (int i = 0; i < 2; ++i) {
      const int c = tid + 256 * i;
      const int row = c >> 3, kq = c & 7;
      const float4 v = wv[i];
      ushort4 h, l;
      h.x = f2bf(v.x); l.x = f2bf(v.x - bf2f(h.x));
      h.y = f2bf(v.y); l.y = f2bf(v.y - bf2f(h.y));
      h.z = f2bf(v.z); l.z = f2bf(v.z - bf2f(h.z));
      h.w = f2bf(v.w); l.w = f2bf(v.w - bf2f(h.w));
      *(ushort4*)&Wh[row * 40 + kq * 4] = h;
      *(ushort4*)&Wl[row * 40 + kq * 4] = l;
    }
    __syncthreads();
    // ---- fragments + MFMA ----
    short8 fah[4], fal[4], fbh[2], fbl[2];
#pragma unroll
    for (int i = 0; i < 4; ++i) {
      const int base = (wm * 64 + i * 16 + fr) * 40 + fg * 8;
      fah[i] = *(const short8*)&Ah[base];
      fal[i] = *(const short8*)&Al[base];
    }
#pragma unroll
    for (int j = 0; j < 2; ++j) {
      const int base = (wn * 32 + j * 16 + fr) * 40 + fg * 8;
      fbh[j] = *(const short8*)&Wh[base];
      fbl[j] = *(const short8*)&Wl[base];
    }
#pragma unroll
    for (int i = 0; i < 4; ++i)
#pragma unroll
      for (int j = 0; j < 2; ++j) {
        acc[i][j] = __builtin_amdgcn_mfma_f32_16x16x32_bf16(fah[i], fbh[j], acc[i][j], 0, 0, 0);
        acc[i][j] = __builtin_amdgcn_mfma_f32_16x16x32_bf16(fah[i], fbl[j], acc[i][j], 0, 0, 0);
        acc[i][j] = __builtin_amdgcn_mfma_f32_16x16x32_bf16(fal[i], fbh[j], acc[i][j], 0, 0, 0);
      }
  }
  // ---- epilogue: C/D layout col=lane&15, row=(lane>>4)*4+reg ----
#pragma unroll
  for (int j = 0; j < 2; ++j) {
    const int col = bn + wn * 32 + j * 16 + fr;
    const float bv = bias[col];
#pragma unroll
    for (int i = 0; i < 4; ++i) {
#pragma unroll
      for (int r = 0; r < 4; ++r) {
        const int row = bm + wm * 64 + i * 16 + fg * 4 + r;
        if (row < M) {
          float v = acc[i][j][r] + bv;
          if (ACT) v = fmaxf(v, 0.f);
          C[(size_t)row * Nn + col] = v;
        }
      }
    }
  }
}

// ---------------- CSR build ----------------
__global__ void fill_zero_i32(int* __restrict__ p, int n) {
  int i = blockIdx.x * blockDim.x + threadIdx.x;
  if (i < n) p[i] = 0;
}
__global__ void fill_zero_f32(float* __restrict__ p, int n) {
  int i = blockIdx.x * blockDim.x + threadIdx.x;
  if (i < n) p[i] = 0.f;
}
__global__ void copy_i32(const int* __restrict__ a, int* __restrict__ b, int n) {
  int i = blockIdx.x * blockDim.x + threadIdx.x;
  if (i < n) b[i] = a[i];
}
__global__ void edge_hist(const int* __restrict__ ei, int E, int Etot, int* __restrict__ counts) {
  int e = blockIdx.x * blockDim.x + threadIdx.x;
  if (e >= Etot) return;
  int d = (e < E) ? ei[E + e] : (e - E);
  atomicAdd(&counts[d], 1);
}
__global__ __launch_bounds__(1024) void scan_excl(const int* __restrict__ counts,
                                                  int* __restrict__ indptr, int n) {
  __shared__ int sm[1024];
  const int tid = threadIdx.x;
  const int chunk = (n + 1023) >> 10;
  const int s = tid * chunk;
  const int e = min(s + chunk, n);
  int loc = 0;
  for (int i = s; i < e; ++i) loc += counts[i];
  sm[tid] = loc;
  __syncthreads();
  for (int off = 1; off < 1024; off <<= 1) {
    int v = (tid >= off) ? sm[tid - off] : 0;
    __syncthreads();
    sm[tid] += v;
    __syncthreads();
  }
  int pre = (tid == 0) ? 0 : sm[tid - 1];
  for (int i = s; i < e; ++i) { indptr[i] = pre; pre += counts[i]; }
  if (tid == 1023) indptr[n] = sm[1023];
}
__global__ void edge_scatter(const int* __restrict__ ei, int E, int Etot,
                             int* __restrict__ cur, int* __restrict__ csr_src,
                             int* __restrict__ csr_eid) {
  int e = blockIdx.x * blockDim.x + threadIdx.x;
  if (e >= Etot) return;
  int s, d;
  if (e < E) { s = ei[e]; d = ei[E + e]; } else { s = e - E; d = s; }
  int p = atomicAdd(&cur[d], 1);
  csr_src[p] = s;
  csr_eid[p] = e;
}

// ---------------- edge attention scores: one wave per edge ----------------
__global__ __launch_bounds__(256) void edge_scores(
    const int* __restrict__ ei, int E, int Etot,
    const float* __restrict__ XL, const float* __restrict__ XR,
    const float* __restrict__ att, float* __restrict__ ES) {
  int e = (int)((blockIdx.x * (size_t)256 + threadIdx.x) >> 6);
  if (e >= Etot) return;
  const int lane = threadIdx.x & 63;
  int src, dst;
  if (e < E) { src = ei[e]; dst = ei[E + e]; } else { src = e - E; dst = src; }
  const int f = lane * 4;   // flat [h*128+c] channel
  const float4 a = *(const float4*)(XL + (size_t)src * F2 + f);
  const float4 b = *(const float4*)(XR + (size_t)dst * F2 + f);
  const float4 t = *(const float4*)(att + f);
  float p = 0.f;
  { float v = a.x + b.x; v = v > 0.f ? v : 0.2f * v; p += v * t.x; }
  { float v = a.y + b.y; v = v > 0.f ? v : 0.2f * v; p += v * t.y; }
  { float v = a.z + b.z; v = v > 0.f ? v : 0.2f * v; p += v * t.z; }
  { float v = a.w + b.w; v = v > 0.f ? v : 0.2f * v; p += v * t.w; }
  p += __shfl_xor(p, 1);
  p += __shfl_xor(p, 2);
  p += __shfl_xor(p, 4);
  p += __shfl_xor(p, 8);
  p += __shfl_xor(p, 16);
  if (lane == 0)       ES[(size_t)e * 2]     = p;
  else if (lane == 32) ES[(size_t)e * 2 + 1] = p;
}

// ---------------- per-node softmax + aggregate: one wave per node ----------------
__global__ __launch_bounds__(256) void node_agg(
    const float* __restrict__ ES, const int* __restrict__ indptr,
    const int* __restrict__ csr_src, const int* __restrict__ csr_eid,
    const float* __restrict__ XL, const float* __restrict__ bias,
    float* __restrict__ OUT, int N) {
  int node = (int)((blockIdx.x * (size_t)256 + threadIdx.x) >> 6);
  if (node >= N) return;
  const int lane = threadIdx.x & 63;
  const int s = indptr[node], e = indptr[node + 1];
  float m0 = -3.4e38f, m1 = -3.4e38f;
  for (int k = s; k < e; ++k) {
    int eid = csr_eid[k];
    m0 = fmaxf(m0, ES[(size_t)eid * 2]);
    m1 = fmaxf(m1, ES[(size_t)eid * 2 + 1]);
  }
  float d0 = 0.f, d1 = 0.f;
  for (int k = s; k < e; ++k) {
    int eid = csr_eid[k];
    d0 += expf(ES[(size_t)eid * 2] - m0);
    d1 += expf(ES[(size_t)eid * 2 + 1] - m1);
  }
  const int h = lane >> 5;
  const float mh = h ? m1 : m0;
  const float dh = h ? d1 : d0;
  const int f = lane * 4;
  float a0 = 0.f, a1 = 0.f, a2 = 0.f, a3 = 0.f;
  for (int k = s; k < e; ++k) {
    int eid = csr_eid[k];
    int sn = csr_src[k];
    float wgt = expf(ES[(size_t)eid * 2 + h] - mh);
    const float4 x = *(const float4*)(XL + (size_t)sn * F2 + f);
    a0 += wgt * x.x; a1 += wgt * x.y; a2 += wgt * x.z; a3 += wgt * x.w;
  }
  const float inv = 1.f / (dh + 1e-16f);
  a0 *= inv; a1 *= inv; a2 *= inv; a3 *= inv;
  float o0 = 0.5f * (a0 + __shfl_xor(a0, 32));
  float o1 = 0.5f * (a1 + __shfl_xor(a1, 32));
  float o2 = 0.5f * (a2 + __shfl_xor(a2, 32));
  float o3 = 0.5f * (a3 + __shfl_xor(a3, 32));
  if (lane < 32) {
    float4 r;
    r.x = fmaxf(o0 + bias[f + 0], 0.f);
    r.y = fmaxf(o1 + bias[f + 1], 0.f);
    r.z = fmaxf(o2 + bias[f + 2], 0.f);
    r.w = fmaxf(o3 + bias[f + 3], 0.f);
    *(float4*)(OUT + (size_t)node * CH + f) = r;
  }
}

// ---------------- gate scalar: one wave per node ----------------
__global__ __launch_bounds__(256) void gate_dot(
    const float* __restrict__ T, const float* __restrict__ w2,
    const float* __restrict__ b2, float* __restrict__ gate, int N) {
  int node = (int)((blockIdx.x * (size_t)256 + threadIdx.x) >> 6);
  if (node >= N) return;
  const int lane = threadIdx.x & 63;
  const float* tr = T + (size_t)node * CH;
  float p = tr[lane] * w2[lane] + tr[lane + 64] * w2[lane + 64];
  p += __shfl_xor(p, 1);
  p += __shfl_xor(p, 2);
  p += __shfl_xor(p, 4);
  p += __shfl_xor(p, 8);
  p += __shfl_xor(p, 16);
  p += __shfl_xor(p, 32);
  if (lane == 0) gate[node] = p + b2[0];
}

// ---------------- pool phase A: per-graph max & denom (one block per graph) -------
__global__ __launch_bounds__(256) void pool_stats(
    const float* __restrict__ gate, const int* __restrict__ batch,
    float* __restrict__ pm, float* __restrict__ pd, int N) {
  const int g = blockIdx.x, tid = threadIdx.x;
  int lo = 0, hi = N;
  while (lo < hi) { int mid = (lo + hi) >> 1; if (batch[mid] < g) lo = mid + 1; else hi = mid; }
  const int s = lo;
  lo = 0; hi = N;
  while (lo < hi) { int mid = (lo + hi) >> 1; if (batch[mid] < g + 1) lo = mid + 1; else hi = mid; }
  const int e = lo;
  __shared__ float red[256];
  float m = -3.4e38f;
  for (int n = s + tid; n < e; n += 256) m = fmaxf(m, gate[n]);
  red[tid] = m; __syncthreads();
  for (int off = 128; off; off >>= 1) {
    if (tid < off) red[tid] = fmaxf(red[tid], red[tid + off]);
    __syncthreads();
  }
  m = red[0]; __syncthreads();
  float d = 0.f;
  for (int n = s + tid; n < e; n += 256) d += expf(gate[n] - m);
  red[tid] = d; __syncthreads();
  for (int off = 128; off; off >>= 1) {
    if (tid < off) red[tid] += red[tid + off];
    __syncthreads();
  }
  if (tid == 0) { pm[g] = m; pd[g] = red[0]; }
}

// ---------------- pool phase B: node-parallel weighted scatter --------------------
__global__ __launch_bounds__(256) void pool_scatter(
    const float* __restrict__ gate, const int* __restrict__ batch,
    const float* __restrict__ pm, const float* __restrict__ pd,
    const float* __restrict__ H, float* __restrict__ Gout, int N) {
  const int idx = blockIdx.x * 256 + threadIdx.x;
  const int node = idx >> 5;
  if (node >= N) return;
  const int lane32 = idx & 31;
  const int g = batch[node];
  const float w = expf(gate[node] - pm[g]) / (pd[g] + 1e-16f);
  const int f = lane32 * 4;
  const float4 x = *(const float4*)(H + (size_t)node * CH + f);
  float* dst = Gout + (size_t)g * CH + f;
  atomicAdd(dst + 0, w * x.x);
  atomicAdd(dst + 1, w * x.y);
  atomicAdd(dst + 2, w * x.z);
  atomicAdd(dst + 3, w * x.w);
}

// ---------------- head MLP + normalize: one block per graph ----------------
__global__ __launch_bounds__(128) void head_kernel(
    const float* __restrict__ Gin, const float* __restrict__ w1, const float* __restrict__ b1,
    const float* __restrict__ w2, const float* __restrict__ b2, float* __restrict__ out) {
  const int g = blockIdx.x, tid = threadIdx.x;
  __shared__ float gs[128], ts[128], o[2];
  gs[tid] = Gin[(size_t)g * CH + tid];
  __syncthreads();
  float a = b1[tid];
  for (int k = 0; k < CH; ++k) a += w1[tid * CH + k] * gs[k];
  ts[tid] = fmaxf(a, 0.f);
  __syncthreads();
  if (tid < 2) {
    float v = b2[tid];
    for (int d2 = 0; d2 < CH; ++d2) v += w2[tid * CH + d2] * ts[d2];
    o[tid] = v;
  }
  __syncthreads();
  if (tid == 0) {
    float nrm = sqrtf(o[0] * o[0] + o[1] * o[1]);
    nrm = fmaxf(nrm, 1e-12f);
    out[g * 2 + 0] = o[0] / nrm;
    out[g * 2 + 1] = o[1] / nrm;
  }
}

extern "C" void kernel_launch(void* const* d_in, const int* in_sizes, int n_in,
                              void* d_out, int out_size, void* d_ws, size_t ws_size,
                              hipStream_t stream) {
  const float* x       = (const float*)d_in[0];
  const int*   ei      = (const int*)d_in[1];
  const int*   batch   = (const int*)d_in[2];
  const float* enc_w1  = (const float*)d_in[3];
  const float* enc_b1  = (const float*)d_in[4];
  const float* enc_w2  = (const float*)d_in[5];
  const float* enc_b2  = (const float*)d_in[6];
  const float* c1_wl   = (const float*)d_in[7];
  const float* c1_bl   = (const float*)d_in[8];
  const float* c1_wr   = (const float*)d_in[9];
  const float* c1_br   = (const float*)d_in[10];
  const float* c1_att  = (const float*)d_in[11];
  const float* c1_bias = (const float*)d_in[12];
  const float* c2_wl   = (const float*)d_in[13];
  const float* c2_bl   = (const float*)d_in[14];
  const float* c2_wr   = (const float*)d_in[15];
  const float* c2_br   = (const float*)d_in[16];
  const float* c2_att  = (const float*)d_in[17];
  const float* c2_bias = (const float*)d_in[18];
  const float* gate_w1 = (const float*)d_in[19];
  const float* gate_b1 = (const float*)d_in[20];
  const float* gate_w2 = (const float*)d_in[21];
  const float* gate_b2 = (const float*)d_in[22];
  const float* head_w1 = (const float*)d_in[23];
  const float* head_b1 = (const float*)d_in[24];
  const float* head_w2 = (const float*)d_in[25];
  const float* head_b2 = (const float*)d_in[26];

  const int N    = in_sizes[2];
  const int E    = in_sizes[1] / 2;
  const int INF_ = in_sizes[0] / N;   // input feature dim (256)
  const int Etot = E + N;

  char* wp = (char*)d_ws;
  auto alloc = [&](size_t bytes) -> void* {
    void* p = (void*)wp;
    wp += (bytes + 255) & ~(size_t)255;
    return p;
  };
  float* XL      = (float*)alloc((size_t)N * F2 * 4);
  float* XR      = (float*)alloc((size_t)N * F2 * 4);
  float* H0      = (float*)alloc((size_t)N * CH * 4);
  float* H1      = (float*)alloc((size_t)N * CH * 4);
  float* ES      = (float*)alloc((size_t)Etot * 2 * 4);
  int*   counts  = (int*)alloc((size_t)N * 4);
  int*   indptr  = (int*)alloc((size_t)(N + 1) * 4);
  int*   cur     = (int*)alloc((size_t)N * 4);
  int*   csr_src = (int*)alloc((size_t)Etot * 4);
  int*   csr_eid = (int*)alloc((size_t)Etot * 4);
  float* gateb   = (float*)alloc((size_t)N * 4);
  float* GS      = (float*)alloc((size_t)NG * CH * 4);
  float* pm      = (float*)alloc((size_t)NG * 4);
  float* pd      = (float*)alloc((size_t)NG * 4);

  const dim3 blk(256);
  const int gM = (N + 127) / 128;

  // encoder
  gemm_nt_mfma<1><<<dim3(gM, CH / 64), blk, 0, stream>>>(x, enc_w1, enc_b1, H0, N, CH, INF_);
  gemm_nt_mfma<1><<<dim3(gM, CH / 64), blk, 0, stream>>>(H0, enc_w2, enc_b2, H1, N, CH, CH);

  // CSR by dst (shared by both convs)
  fill_zero_i32<<<(N + 255) / 256, blk, 0, stream>>>(counts, N);
  edge_hist<<<(Etot + 255) / 256, blk, 0, stream>>>(ei, E, Etot, counts);
  scan_excl<<<1, 1024, 0, stream>>>(counts, indptr, N);
  copy_i32<<<(N + 255) / 256, blk, 0, stream>>>(indptr, cur, N);
  edge_scatter<<<(Etot + 255) / 256, blk, 0, stream>>>(ei, E, Etot, cur, csr_src, csr_eid);

  // conv1
  gemm_nt_mfma<0><<<dim3(gM, F2 / 64), blk, 0, stream>>>(H1, c1_wl, c1_bl, XL, N, F2, CH);
  gemm_nt_mfma<0><<<dim3(gM, F2 / 64), blk, 0, stream>>>(H1, c1_wr, c1_br, XR, N, F2, CH);
  edge_scores<<<(Etot + 3) / 4, blk, 0, stream>>>(ei, E, Etot, XL, XR, c1_att, ES);
  node_agg<<<(N + 3) / 4, blk, 0, stream>>>(ES, indptr, csr_src, csr_eid, XL, c1_bias, H0, N);

  // conv2
  gemm_nt_mfma<0><<<dim3(gM, F2 / 64), blk, 0, stream>>>(H0, c2_wl, c2_bl, XL, N, F2, CH);
  gemm_nt_mfma<0><<<dim3(gM, F2 / 64), blk, 0, stream>>>(H0, c2_wr, c2_br, XR, N, F2, CH);
  edge_scores<<<(Etot + 3) / 4, blk, 0, stream>>>(ei, E, Etot, XL, XR, c2_att, ES);
  node_agg<<<(N + 3) / 4, blk, 0, stream>>>(ES, indptr, csr_src, csr_eid, XL, c2_bias, H1, N);

  // gate MLP (t = relu(h3 @ gw1^T + gb1) into XL scratch), then scalar gate
  gemm_nt_mfma<1><<<dim3(gM, CH / 64), blk, 0, stream>>>(H1, gate_w1, gate_b1, XL, N, CH, CH);
  gate_dot<<<(N + 3) / 4, blk, 0, stream>>>(XL, gate_w2, gate_b2, gateb, N);

  // pooling: stats -> zero -> scatter
  pool_stats<<<NG, blk, 0, stream>>>(gateb, batch, pm, pd, N);
  fill_zero_f32<<<(NG * CH + 255) / 256, blk, 0, stream>>>(GS, NG * CH);
  pool_scatter<<<((N * 32) + 255) / 256, blk, 0, stream>>>(gateb, batch, pm, pd, H1, GS, N);

  // head + normalize
  head_kernel<<<NG, 128, 0, stream>>>(GS, head_w1, head_b1, head_w2, head_b2, (float*)d_out);
}

// Round 3
// 1142.984 us; speedup vs baseline: 1.2840x; 1.1679x over previous
//
#include <hip/hip_runtime.h>
#include <math.h>

#define CH 128          // HID
#define F2 256          // HEADS*CH
#define NG 64           // graphs
#define PS 16           // pool sub-blocks per graph

typedef __attribute__((ext_vector_type(8))) short short8;
typedef __attribute__((ext_vector_type(4))) float f32x4;

// truncating fp32 -> bf16 split: hi = trunc(x), lo = trunc(x - hi). Exact remainder,
// total representation error <= ~2^-15 relative — far below the 2e-2 threshold.
__device__ inline ushort f2bf_t(float x) { return (ushort)(__float_as_uint(x) >> 16); }
__device__ inline float bf2f(ushort h) { return __uint_as_float(((uint)h) << 16); }

// ---------------- split-bf16 MFMA GEMM: C[M,Nn] = act(A[M,K] @ W[Nn,K]^T + bias) ----
template<int ACT>
__global__ __launch_bounds__(256) void gemm_nt_mfma(
    const float* __restrict__ A, const float* __restrict__ W,
    const float* __restrict__ bias, float* __restrict__ C,
    int M, int Nn, int K) {
  // tile 128(M) x 64(N), BK=32. LDS rows padded to 40 bf16 (80B) -> b128 conflict-free.
  __shared__ ushort Ah[128 * 40], Al[128 * 40], Wh[64 * 40], Wl[64 * 40];
  const int tid = threadIdx.x;
  const int lane = tid & 63;
  const int wid = tid >> 6;
  const int wm = wid >> 1, wn = wid & 1;          // 2x2 waves, each 64x32
  const int bm = blockIdx.x * 128, bn = blockIdx.y * 64;
  const int fr = lane & 15, fg = lane >> 4;

  f32x4 acc[4][2];
#pragma unroll
  for (int i = 0; i < 4; ++i)
#pragma unroll
    for (int j = 0; j < 2; ++j) acc[i][j] = (f32x4)0.f;

  for (int k0 = 0; k0 < K; k0 += 32) {
    float4 av[4], wv[2];
#pragma unroll
    for (int i = 0; i < 4; ++i) {
      const int c = tid + 256 * i;          // 1024 float4 chunks: 128 rows x 8
      const int row = c >> 3, kq = c & 7;
      const int gr = bm + row;
      av[i] = (gr < M) ? *(const float4*)(A + (size_t)gr * K + k0 + kq * 4)
                       : make_float4(0.f, 0.f, 0.f, 0.f);
    }
#pragma unroll
    for (int i = 0; i < 2; ++i) {
      const int c = tid + 256 * i;          // 512 chunks: 64 rows x 8
      const int row = c >> 3, kq = c & 7;
      wv[i] = *(const float4*)(W + (size_t)(bn + row) * K + k0 + kq * 4);
    }
    __syncthreads();
#pragma unroll
    for (int i = 0; i < 4; ++i) {
      const int c = tid + 256 * i;
      const int row = c >> 3, kq = c & 7;
      const float4 v = av[i];
      ushort4 h, l;
      h.x = f2bf_t(v.x); l.x = f2bf_t(v.x - bf2f(h.x));
      h.y = f2bf_t(v.y); l.y = f2bf_t(v.y - bf2f(h.y));
      h.z = f2bf_t(v.z); l.z = f2bf_t(v.z - bf2f(h.z));
      h.w = f2bf_t(v.w); l.w = f2bf_t(v.w - bf2f(h.w));
      *(ushort4*)&Ah[row * 40 + kq * 4] = h;
      *(ushort4*)&Al[row * 40 + kq * 4] = l;
    }
#pragma unroll
    for (int i = 0; i < 2; ++i) {
      const int c = tid + 256 * i;
      const int row = c >> 3, kq = c & 7;
      const float4 v = wv[i];
      ushort4 h, l;
      h.x = f2bf_t(v.x); l.x = f2bf_t(v.x - bf2f(h.x));
      h.y = f2bf_t(v.y); l.y = f2bf_t(v.y - bf2f(h.y));
      h.z = f2bf_t(v.z); l.z = f2bf_t(v.z - bf2f(h.z));
      h.w = f2bf_t(v.w); l.w = f2bf_t(v.w - bf2f(h.w));
      *(ushort4*)&Wh[row * 40 + kq * 4] = h;
      *(ushort4*)&Wl[row * 40 + kq * 4] = l;
    }
    __syncthreads();
    short8 fah[4], fal[4], fbh[2], fbl[2];
#pragma unroll
    for (int i = 0; i < 4; ++i) {
      const int base = (wm * 64 + i * 16 + fr) * 40 + fg * 8;
      fah[i] = *(const short8*)&Ah[base];
      fal[i] = *(const short8*)&Al[base];
    }
#pragma unroll
    for (int j = 0; j < 2; ++j) {
      const int base = (wn * 32 + j * 16 + fr) * 40 + fg * 8;
      fbh[j] = *(const short8*)&Wh[base];
      fbl[j] = *(const short8*)&Wl[base];
    }
#pragma unroll
    for (int i = 0; i < 4; ++i)
#pragma unroll
      for (int j = 0; j < 2; ++j) {
        acc[i][j] = __builtin_amdgcn_mfma_f32_16x16x32_bf16(fah[i], fbh[j], acc[i][j], 0, 0, 0);
        acc[i][j] = __builtin_amdgcn_mfma_f32_16x16x32_bf16(fah[i], fbl[j], acc[i][j], 0, 0, 0);
        acc[i][j] = __builtin_amdgcn_mfma_f32_16x16x32_bf16(fal[i], fbh[j], acc[i][j], 0, 0, 0);
      }
  }
  // epilogue: C/D layout col=lane&15, row=(lane>>4)*4+reg
#pragma unroll
  for (int j = 0; j < 2; ++j) {
    const int col = bn + wn * 32 + j * 16 + fr;
    const float bv = bias[col];
#pragma unroll
    for (int i = 0; i < 4; ++i) {
#pragma unroll
      for (int r = 0; r < 4; ++r) {
        const int row = bm + wm * 64 + i * 16 + fg * 4 + r;
        if (row < M) {
          float v = acc[i][j][r] + bv;
          if (ACT) v = fmaxf(v, 0.f);
          C[(size_t)row * Nn + col] = v;
        }
      }
    }
  }
}

// ---------------- CSR build ----------------
__global__ void fill_zero_i32(int* __restrict__ p, int n) {
  int i = blockIdx.x * blockDim.x + threadIdx.x;
  if (i < n) p[i] = 0;
}
__global__ void copy_i32(const int* __restrict__ a, int* __restrict__ b, int n) {
  int i = blockIdx.x * blockDim.x + threadIdx.x;
  if (i < n) b[i] = a[i];
}
__global__ void edge_hist(const int* __restrict__ ei, int E, int Etot, int* __restrict__ counts) {
  int e = blockIdx.x * blockDim.x + threadIdx.x;
  if (e >= Etot) return;
  int d = (e < E) ? ei[E + e] : (e - E);
  atomicAdd(&counts[d], 1);
}
__global__ __launch_bounds__(1024) void scan_excl(const int* __restrict__ counts,
                                                  int* __restrict__ indptr, int n) {
  __shared__ int sm[1024];
  const int tid = threadIdx.x;
  const int chunk = (n + 1023) >> 10;
  const int s = tid * chunk;
  const int e = min(s + chunk, n);
  int loc = 0;
  for (int i = s; i < e; ++i) loc += counts[i];
  sm[tid] = loc;
  __syncthreads();
  for (int off = 1; off < 1024; off <<= 1) {
    int v = (tid >= off) ? sm[tid - off] : 0;
    __syncthreads();
    sm[tid] += v;
    __syncthreads();
  }
  int pre = (tid == 0) ? 0 : sm[tid - 1];
  for (int i = s; i < e; ++i) { indptr[i] = pre; pre += counts[i]; }
  if (tid == 1023) indptr[n] = sm[1023];
}
__global__ void edge_scatter(const int* __restrict__ ei, int E, int Etot,
                             int* __restrict__ cur, int* __restrict__ csr_src,
                             int* __restrict__ csr_eid) {
  int e = blockIdx.x * blockDim.x + threadIdx.x;
  if (e >= Etot) return;
  int s, d;
  if (e < E) { s = ei[e]; d = ei[E + e]; } else { s = e - E; d = s; }
  int p = atomicAdd(&cur[d], 1);
  csr_src[p] = s;
  csr_eid[p] = e;
}

// ---------------- edge attention scores: one wave per edge ----------------
__global__ __launch_bounds__(256) void edge_scores(
    const int* __restrict__ ei, int E, int Etot,
    const float* __restrict__ XL, const float* __restrict__ XR,
    const float* __restrict__ att, float* __restrict__ ES) {
  int e = (int)((blockIdx.x * (size_t)256 + threadIdx.x) >> 6);
  if (e >= Etot) return;
  const int lane = threadIdx.x & 63;
  int src, dst;
  if (e < E) { src = ei[e]; dst = ei[E + e]; } else { src = e - E; dst = src; }
  const int f = lane * 4;   // flat [h*128+c] channel
  const float4 a = *(const float4*)(XL + (size_t)src * F2 + f);
  const float4 b = *(const float4*)(XR + (size_t)dst * F2 + f);
  const float4 t = *(const float4*)(att + f);
  float p = 0.f;
  { float v = a.x + b.x; v = v > 0.f ? v : 0.2f * v; p += v * t.x; }
  { float v = a.y + b.y; v = v > 0.f ? v : 0.2f * v; p += v * t.y; }
  { float v = a.z + b.z; v = v > 0.f ? v : 0.2f * v; p += v * t.z; }
  { float v = a.w + b.w; v = v > 0.f ? v : 0.2f * v; p += v * t.w; }
  p += __shfl_xor(p, 1);
  p += __shfl_xor(p, 2);
  p += __shfl_xor(p, 4);
  p += __shfl_xor(p, 8);
  p += __shfl_xor(p, 16);
  if (lane == 0)       ES[(size_t)e * 2]     = p;
  else if (lane == 32) ES[(size_t)e * 2 + 1] = p;
}

// ---------------- per-node softmax + aggregate: one wave per node ----------------
__global__ __launch_bounds__(256) void node_agg(
    const float* __restrict__ ES, const int* __restrict__ indptr,
    const int* __restrict__ csr_src, const int* __restrict__ csr_eid,
    const float* __restrict__ XL, const float* __restrict__ bias,
    float* __restrict__ OUT, int N) {
  int node = (int)((blockIdx.x * (size_t)256 + threadIdx.x) >> 6);
  if (node >= N) return;
  const int lane = threadIdx.x & 63;
  const int s = indptr[node], e = indptr[node + 1];
  float m0 = -3.4e38f, m1 = -3.4e38f;
  for (int k = s; k < e; ++k) {
    int eid = csr_eid[k];
    m0 = fmaxf(m0, ES[(size_t)eid * 2]);
    m1 = fmaxf(m1, ES[(size_t)eid * 2 + 1]);
  }
  float d0 = 0.f, d1 = 0.f;
  for (int k = s; k < e; ++k) {
    int eid = csr_eid[k];
    d0 += expf(ES[(size_t)eid * 2] - m0);
    d1 += expf(ES[(size_t)eid * 2 + 1] - m1);
  }
  const int h = lane >> 5;
  const float mh = h ? m1 : m0;
  const float dh = h ? d1 : d0;
  const int f = lane * 4;
  float a0 = 0.f, a1 = 0.f, a2 = 0.f, a3 = 0.f;
  for (int k = s; k < e; ++k) {
    int eid = csr_eid[k];
    int sn = csr_src[k];
    float wgt = expf(ES[(size_t)eid * 2 + h] - mh);
    const float4 x = *(const float4*)(XL + (size_t)sn * F2 + f);
    a0 += wgt * x.x; a1 += wgt * x.y; a2 += wgt * x.z; a3 += wgt * x.w;
  }
  const float inv = 1.f / (dh + 1e-16f);
  a0 *= inv; a1 *= inv; a2 *= inv; a3 *= inv;
  float o0 = 0.5f * (a0 + __shfl_xor(a0, 32));
  float o1 = 0.5f * (a1 + __shfl_xor(a1, 32));
  float o2 = 0.5f * (a2 + __shfl_xor(a2, 32));
  float o3 = 0.5f * (a3 + __shfl_xor(a3, 32));
  if (lane < 32) {
    float4 r;
    r.x = fmaxf(o0 + bias[f + 0], 0.f);
    r.y = fmaxf(o1 + bias[f + 1], 0.f);
    r.z = fmaxf(o2 + bias[f + 2], 0.f);
    r.w = fmaxf(o3 + bias[f + 3], 0.f);
    *(float4*)(OUT + (size_t)node * CH + f) = r;
  }
}

// ---------------- gate scalar: one wave per node ----------------
__global__ __launch_bounds__(256) void gate_dot(
    const float* __restrict__ T, const float* __restrict__ w2,
    const float* __restrict__ b2, float* __restrict__ gate, int N) {
  int node = (int)((blockIdx.x * (size_t)256 + threadIdx.x) >> 6);
  if (node >= N) return;
  const int lane = threadIdx.x & 63;
  const float* tr = T + (size_t)node * CH;
  float p = tr[lane] * w2[lane] + tr[lane + 64] * w2[lane + 64];
  p += __shfl_xor(p, 1);
  p += __shfl_xor(p, 2);
  p += __shfl_xor(p, 4);
  p += __shfl_xor(p, 8);
  p += __shfl_xor(p, 16);
  p += __shfl_xor(p, 32);
  if (lane == 0) gate[node] = p + b2[0];
}

// ---------------- pool phase A: per-graph max & denom (one block per graph) -------
__global__ __launch_bounds__(256) void pool_stats(
    const float* __restrict__ gate, const int* __restrict__ batch,
    float* __restrict__ pm, float* __restrict__ pd, int N) {
  const int g = blockIdx.x, tid = threadIdx.x;
  int lo = 0, hi = N;
  while (lo < hi) { int mid = (lo + hi) >> 1; if (batch[mid] < g) lo = mid + 1; else hi = mid; }
  const int s = lo;
  lo = 0; hi = N;
  while (lo < hi) { int mid = (lo + hi) >> 1; if (batch[mid] < g + 1) lo = mid + 1; else hi = mid; }
  const int e = lo;
  __shared__ float red[256];
  float m = -3.4e38f;
  for (int n = s + tid; n < e; n += 256) m = fmaxf(m, gate[n]);
  red[tid] = m; __syncthreads();
  for (int off = 128; off; off >>= 1) {
    if (tid < off) red[tid] = fmaxf(red[tid], red[tid + off]);
    __syncthreads();
  }
  m = red[0]; __syncthreads();
  float d = 0.f;
  for (int n = s + tid; n < e; n += 256) d += expf(gate[n] - m);
  red[tid] = d; __syncthreads();
  for (int off = 128; off; off >>= 1) {
    if (tid < off) red[tid] += red[tid + off];
    __syncthreads();
  }
  if (tid == 0) { pm[g] = m; pd[g] = red[0]; }
}

// ---------------- pool phase B: deterministic partial sums (no atomics) -----------
// grid = NG*PS blocks of 128; block (g, j) accumulates channel tid over its node
// slice of graph g into PART[(g*PS+j)*CH+tid].
__global__ __launch_bounds__(128) void pool_partial(
    const float* __restrict__ gate, const int* __restrict__ batch,
    const float* __restrict__ pm, const float* __restrict__ pd,
    const float* __restrict__ H, float* __restrict__ PART, int N) {
  const int g = blockIdx.x / PS, j = blockIdx.x % PS;
  const int tid = threadIdx.x;
  int lo = 0, hi = N;
  while (lo < hi) { int mid = (lo + hi) >> 1; if (batch[mid] < g) lo = mid + 1; else hi = mid; }
  const int s = lo;
  lo = 0; hi = N;
  while (lo < hi) { int mid = (lo + hi) >> 1; if (batch[mid] < g + 1) lo = mid + 1; else hi = mid; }
  const int e = lo;
  const int len = e - s;
  const int per = (len + PS - 1) / PS;
  const int ns = s + j * per;
  const int ne = min(ns + per, e);
  const float m = pm[g];
  const float inv = 1.f / (pd[g] + 1e-16f);
  float acc = 0.f;
  for (int n = ns; n < ne; ++n) {
    const float w = expf(gate[n] - m);
    acc += w * H[(size_t)n * CH + tid];
  }
  PART[(size_t)blockIdx.x * CH + tid] = acc * inv;
}
__global__ __launch_bounds__(128) void pool_reduce(
    const float* __restrict__ PART, float* __restrict__ Gout) {
  const int g = blockIdx.x, tid = threadIdx.x;
  float acc = 0.f;
#pragma unroll
  for (int j = 0; j < PS; ++j) acc += PART[(size_t)(g * PS + j) * CH + tid];
  Gout[(size_t)g * CH + tid] = acc;
}

// ---------------- head MLP + normalize: one block per graph ----------------
__global__ __launch_bounds__(128) void head_kernel(
    const float* __restrict__ Gin, const float* __restrict__ w1, const float* __restrict__ b1,
    const float* __restrict__ w2, const float* __restrict__ b2, float* __restrict__ out) {
  const int g = blockIdx.x, tid = threadIdx.x;
  __shared__ float gs[128], ts[128], o[2];
  gs[tid] = Gin[(size_t)g * CH + tid];
  __syncthreads();
  float a = b1[tid];
  for (int k = 0; k < CH; ++k) a += w1[tid * CH + k] * gs[k];
  ts[tid] = fmaxf(a, 0.f);
  __syncthreads();
  if (tid < 2) {
    float v = b2[tid];
    for (int d2 = 0; d2 < CH; ++d2) v += w2[tid * CH + d2] * ts[d2];
    o[tid] = v;
  }
  __syncthreads();
  if (tid == 0) {
    float nrm = sqrtf(o[0] * o[0] + o[1] * o[1]);
    nrm = fmaxf(nrm, 1e-12f);
    out[g * 2 + 0] = o[0] / nrm;
    out[g * 2 + 1] = o[1] / nrm;
  }
}

extern "C" void kernel_launch(void* const* d_in, const int* in_sizes, int n_in,
                              void* d_out, int out_size, void* d_ws, size_t ws_size,
                              hipStream_t stream) {
  const float* x       = (const float*)d_in[0];
  const int*   ei      = (const int*)d_in[1];
  const int*   batch   = (const int*)d_in[2];
  const float* enc_w1  = (const float*)d_in[3];
  const float* enc_b1  = (const float*)d_in[4];
  const float* enc_w2  = (const float*)d_in[5];
  const float* enc_b2  = (const float*)d_in[6];
  const float* c1_wl   = (const float*)d_in[7];
  const float* c1_bl   = (const float*)d_in[8];
  const float* c1_wr   = (const float*)d_in[9];
  const float* c1_br   = (const float*)d_in[10];
  const float* c1_att  = (const float*)d_in[11];
  const float* c1_bias = (const float*)d_in[12];
  const float* c2_wl   = (const float*)d_in[13];
  const float* c2_bl   = (const float*)d_in[14];
  const float* c2_wr   = (const float*)d_in[15];
  const float* c2_br   = (const float*)d_in[16];
  const float* c2_att  = (const float*)d_in[17];
  const float* c2_bias = (const float*)d_in[18];
  const float* gate_w1 = (const float*)d_in[19];
  const float* gate_b1 = (const float*)d_in[20];
  const float* gate_w2 = (const float*)d_in[21];
  const float* gate_b2 = (const float*)d_in[22];
  const float* head_w1 = (const float*)d_in[23];
  const float* head_b1 = (const float*)d_in[24];
  const float* head_w2 = (const float*)d_in[25];
  const float* head_b2 = (const float*)d_in[26];

  const int N    = in_sizes[2];
  const int E    = in_sizes[1] / 2;
  const int INF_ = in_sizes[0] / N;   // input feature dim (256)
  const int Etot = E + N;

  char* wp = (char*)d_ws;
  auto alloc = [&](size_t bytes) -> void* {
    void* p = (void*)wp;
    wp += (bytes + 255) & ~(size_t)255;
    return p;
  };
  float* XL      = (float*)alloc((size_t)N * F2 * 4);
  float* XR      = (float*)alloc((size_t)N * F2 * 4);
  float* H0      = (float*)alloc((size_t)N * CH * 4);
  float* H1      = (float*)alloc((size_t)N * CH * 4);
  float* ES      = (float*)alloc((size_t)Etot * 2 * 4);
  int*   counts  = (int*)alloc((size_t)N * 4);
  int*   indptr  = (int*)alloc((size_t)(N + 1) * 4);
  int*   cur     = (int*)alloc((size_t)N * 4);
  int*   csr_src = (int*)alloc((size_t)Etot * 4);
  int*   csr_eid = (int*)alloc((size_t)Etot * 4);
  float* gateb   = (float*)alloc((size_t)N * 4);
  float* GS      = (float*)alloc((size_t)NG * CH * 4);
  float* pm      = (float*)alloc((size_t)NG * 4);
  float* pd      = (float*)alloc((size_t)NG * 4);
  float* PART    = (float*)alloc((size_t)NG * PS * CH * 4);

  const dim3 blk(256);
  const int gM = (N + 127) / 128;

  // encoder
  gemm_nt_mfma<1><<<dim3(gM, CH / 64), blk, 0, stream>>>(x, enc_w1, enc_b1, H0, N, CH, INF_);
  gemm_nt_mfma<1><<<dim3(gM, CH / 64), blk, 0, stream>>>(H0, enc_w2, enc_b2, H1, N, CH, CH);

  // CSR by dst (shared by both convs)
  fill_zero_i32<<<(N + 255) / 256, blk, 0, stream>>>(counts, N);
  edge_hist<<<(Etot + 255) / 256, blk, 0, stream>>>(ei, E, Etot, counts);
  scan_excl<<<1, 1024, 0, stream>>>(counts, indptr, N);
  copy_i32<<<(N + 255) / 256, blk, 0, stream>>>(indptr, cur, N);
  edge_scatter<<<(Etot + 255) / 256, blk, 0, stream>>>(ei, E, Etot, cur, csr_src, csr_eid);

  // conv1
  gemm_nt_mfma<0><<<dim3(gM, F2 / 64), blk, 0, stream>>>(H1, c1_wl, c1_bl, XL, N, F2, CH);
  gemm_nt_mfma<0><<<dim3(gM, F2 / 64), blk, 0, stream>>>(H1, c1_wr, c1_br, XR, N, F2, CH);
  edge_scores<<<(Etot + 3) / 4, blk, 0, stream>>>(ei, E, Etot, XL, XR, c1_att, ES);
  node_agg<<<(N + 3) / 4, blk, 0, stream>>>(ES, indptr, csr_src, csr_eid, XL, c1_bias, H0, N);

  // conv2
  gemm_nt_mfma<0><<<dim3(gM, F2 / 64), blk, 0, stream>>>(H0, c2_wl, c2_bl, XL, N, F2, CH);
  gemm_nt_mfma<0><<<dim3(gM, F2 / 64), blk, 0, stream>>>(H0, c2_wr, c2_br, XR, N, F2, CH);
  edge_scores<<<(Etot + 3) / 4, blk, 0, stream>>>(ei, E, Etot, XL, XR, c2_att, ES);
  node_agg<<<(N + 3) / 4, blk, 0, stream>>>(ES, indptr, csr_src, csr_eid, XL, c2_bias, H1, N);

  // gate MLP (t = relu(h3 @ gw1^T + gb1) into XL scratch), then scalar gate
  gemm_nt_mfma<1><<<dim3(gM, CH / 64), blk, 0, stream>>>(H1, gate_w1, gate_b1, XL, N, CH, CH);
  gate_dot<<<(N + 3) / 4, blk, 0, stream>>>(XL, gate_w2, gate_b2, gateb, N);

  // pooling: stats -> deterministic partials -> reduce
  pool_stats<<<NG, blk, 0, stream>>>(gateb, batch, pm, pd, N);
  pool_partial<<<NG * PS, 128, 0, stream>>>(gateb, batch, pm, pd, H1, PART, N);
  pool_reduce<<<NG, 128, 0, stream>>>(PART, GS);

  // head + normalize
  head_kernel<<<NG, 128, 0, stream>>>(GS, head_w1, head_b1, head_w2, head_b2, (float*)d_out);
}

// Round 4
// 648.240 us; speedup vs baseline: 2.2640x; 1.7632x over previous
//
#include <hip/hip_runtime.h>
#include <math.h>

#define CH 128          // HID
#define F2 256          // HEADS*CH
#define NG 64           // graphs
#define PS 16           // pool sub-blocks per graph

typedef __attribute__((ext_vector_type(8))) short short8;
typedef __attribute__((ext_vector_type(4))) float f32x4;

// truncating fp32 -> bf16 split (exact residual; used inside GEMM staging)
__device__ inline ushort f2bf_t(float x) { return (ushort)(__float_as_uint(x) >> 16); }
// round-nearest-even fp32 -> bf16 (used for stored bf16 outputs)
__device__ inline ushort f2bf_r(float x) {
  uint u = __float_as_uint(x);
  return (ushort)((u + 0x7fffu + ((u >> 16) & 1u)) >> 16);
}
__device__ inline float bf2f(ushort h) { return __uint_as_float(((uint)h) << 16); }

// ---------------- split-bf16 MFMA GEMM: C[M,Nn] = act(A[M,K] @ W[Nn,K]^T + bias) ----
// OBF=1: additionally-instead write bf16 output to Cb (round-nearest).
template<int ACT, int OBF>
__global__ __launch_bounds__(256) void gemm_nt_mfma(
    const float* __restrict__ A, const float* __restrict__ W,
    const float* __restrict__ bias, float* __restrict__ C, ushort* __restrict__ Cb,
    int M, int Nn, int K) {
  // tile 128(M) x 64(N), BK=32. LDS rows padded to 40 bf16 (80B) -> b128 conflict-free.
  __shared__ ushort Ah[128 * 40], Al[128 * 40], Wh[64 * 40], Wl[64 * 40];
  const int tid = threadIdx.x;
  const int lane = tid & 63;
  const int wid = tid >> 6;
  const int wm = wid >> 1, wn = wid & 1;          // 2x2 waves, each 64x32
  const int bm = blockIdx.x * 128, bn = blockIdx.y * 64;
  const int fr = lane & 15, fg = lane >> 4;

  f32x4 acc[4][2];
#pragma unroll
  for (int i = 0; i < 4; ++i)
#pragma unroll
    for (int j = 0; j < 2; ++j) acc[i][j] = (f32x4)0.f;

  for (int k0 = 0; k0 < K; k0 += 32) {
    float4 av[4], wv[2];
#pragma unroll
    for (int i = 0; i < 4; ++i) {
      const int c = tid + 256 * i;          // 1024 float4 chunks: 128 rows x 8
      const int row = c >> 3, kq = c & 7;
      const int gr = bm + row;
      av[i] = (gr < M) ? *(const float4*)(A + (size_t)gr * K + k0 + kq * 4)
                       : make_float4(0.f, 0.f, 0.f, 0.f);
    }
#pragma unroll
    for (int i = 0; i < 2; ++i) {
      const int c = tid + 256 * i;          // 512 chunks: 64 rows x 8
      const int row = c >> 3, kq = c & 7;
      wv[i] = *(const float4*)(W + (size_t)(bn + row) * K + k0 + kq * 4);
    }
    __syncthreads();
#pragma unroll
    for (int i = 0; i < 4; ++i) {
      const int c = tid + 256 * i;
      const int row = c >> 3, kq = c & 7;
      const float4 v = av[i];
      ushort4 h, l;
      h.x = f2bf_t(v.x); l.x = f2bf_t(v.x - bf2f(h.x));
      h.y = f2bf_t(v.y); l.y = f2bf_t(v.y - bf2f(h.y));
      h.z = f2bf_t(v.z); l.z = f2bf_t(v.z - bf2f(h.z));
      h.w = f2bf_t(v.w); l.w = f2bf_t(v.w - bf2f(h.w));
      *(ushort4*)&Ah[row * 40 + kq * 4] = h;
      *(ushort4*)&Al[row * 40 + kq * 4] = l;
    }
#pragma unroll
    for (int i = 0; i < 2; ++i) {
      const int c = tid + 256 * i;
      const int row = c >> 3, kq = c & 7;
      const float4 v = wv[i];
      ushort4 h, l;
      h.x = f2bf_t(v.x); l.x = f2bf_t(v.x - bf2f(h.x));
      h.y = f2bf_t(v.y); l.y = f2bf_t(v.y - bf2f(h.y));
      h.z = f2bf_t(v.z); l.z = f2bf_t(v.z - bf2f(h.z));
      h.w = f2bf_t(v.w); l.w = f2bf_t(v.w - bf2f(h.w));
      *(ushort4*)&Wh[row * 40 + kq * 4] = h;
      *(ushort4*)&Wl[row * 40 + kq * 4] = l;
    }
    __syncthreads();
    short8 fah[4], fal[4], fbh[2], fbl[2];
#pragma unroll
    for (int i = 0; i < 4; ++i) {
      const int base = (wm * 64 + i * 16 + fr) * 40 + fg * 8;
      fah[i] = *(const short8*)&Ah[base];
      fal[i] = *(const short8*)&Al[base];
    }
#pragma unroll
    for (int j = 0; j < 2; ++j) {
      const int base = (wn * 32 + j * 16 + fr) * 40 + fg * 8;
      fbh[j] = *(const short8*)&Wh[base];
      fbl[j] = *(const short8*)&Wl[base];
    }
#pragma unroll
    for (int i = 0; i < 4; ++i)
#pragma unroll
      for (int j = 0; j < 2; ++j) {
        acc[i][j] = __builtin_amdgcn_mfma_f32_16x16x32_bf16(fah[i], fbh[j], acc[i][j], 0, 0, 0);
        acc[i][j] = __builtin_amdgcn_mfma_f32_16x16x32_bf16(fah[i], fbl[j], acc[i][j], 0, 0, 0);
        acc[i][j] = __builtin_amdgcn_mfma_f32_16x16x32_bf16(fal[i], fbh[j], acc[i][j], 0, 0, 0);
      }
  }
  // epilogue: C/D layout col=lane&15, row=(lane>>4)*4+reg
#pragma unroll
  for (int j = 0; j < 2; ++j) {
    const int col = bn + wn * 32 + j * 16 + fr;
    const float bv = bias[col];
#pragma unroll
    for (int i = 0; i < 4; ++i) {
#pragma unroll
      for (int r = 0; r < 4; ++r) {
        const int row = bm + wm * 64 + i * 16 + fg * 4 + r;
        if (row < M) {
          float v = acc[i][j][r] + bv;
          if (ACT) v = fmaxf(v, 0.f);
          if (OBF) Cb[(size_t)row * Nn + col] = f2bf_r(v);
          else     C[(size_t)row * Nn + col] = v;
        }
      }
    }
  }
}

// ---------------- CSR build ----------------
__global__ void fill_zero_i32(int* __restrict__ p, int n) {
  int i = blockIdx.x * blockDim.x + threadIdx.x;
  if (i < n) p[i] = 0;
}
__global__ void copy_i32(const int* __restrict__ a, int* __restrict__ b, int n) {
  int i = blockIdx.x * blockDim.x + threadIdx.x;
  if (i < n) b[i] = a[i];
}
__global__ void edge_hist(const int* __restrict__ ei, int E, int Etot, int* __restrict__ counts) {
  int e = blockIdx.x * blockDim.x + threadIdx.x;
  if (e >= Etot) return;
  int d = (e < E) ? ei[E + e] : (e - E);
  atomicAdd(&counts[d], 1);
}
__global__ __launch_bounds__(1024) void scan_excl(const int* __restrict__ counts,
                                                  int* __restrict__ indptr, int n) {
  __shared__ int sm[1024];
  const int tid = threadIdx.x;
  const int chunk = (n + 1023) >> 10;
  const int s = tid * chunk;
  const int e = min(s + chunk, n);
  int loc = 0;
  for (int i = s; i < e; ++i) loc += counts[i];
  sm[tid] = loc;
  __syncthreads();
  for (int off = 1; off < 1024; off <<= 1) {
    int v = (tid >= off) ? sm[tid - off] : 0;
    __syncthreads();
    sm[tid] += v;
    __syncthreads();
  }
  int pre = (tid == 0) ? 0 : sm[tid - 1];
  for (int i = s; i < e; ++i) { indptr[i] = pre; pre += counts[i]; }
  if (tid == 1023) indptr[n] = sm[1023];
}
__global__ void edge_scatter(const int* __restrict__ ei, int E, int Etot,
                             int* __restrict__ cur, int* __restrict__ csr_src) {
  int e = blockIdx.x * blockDim.x + threadIdx.x;
  if (e >= Etot) return;
  int s, d;
  if (e < E) { s = ei[e]; d = ei[E + e]; } else { s = e - E; d = s; }
  int p = atomicAdd(&cur[d], 1);
  csr_src[p] = s;
}

// -------- fused GATv2 message pass: one wave per dst node, online softmax --------
// XLb: bf16 [N, F2] (gathered by src). XR: f32 [N, F2] (sequential by dst).
__global__ __launch_bounds__(256) void fused_conv(
    const int* __restrict__ indptr, const int* __restrict__ csr_src,
    const ushort* __restrict__ XLb, const float* __restrict__ XR,
    const float* __restrict__ att, const float* __restrict__ bias,
    float* __restrict__ OUT, int N) {
  int node = (int)((blockIdx.x * (size_t)256 + threadIdx.x) >> 6);
  if (node >= N) return;
  const int lane = threadIdx.x & 63;
  const int f = lane * 4;                     // flat channel h*128+c, h = lane>>5
  const float4 xr = *(const float4*)(XR + (size_t)node * F2 + f);
  const float4 at = *(const float4*)(att + f);
  const int s = indptr[node], e = indptr[node + 1];
  float m = -3.4e38f, dsum = 0.f;
  float a0 = 0.f, a1 = 0.f, a2 = 0.f, a3 = 0.f;
  for (int k = s; k < e; ++k) {
    const int sn = csr_src[k];
    const ushort4 xb = *(const ushort4*)(XLb + (size_t)sn * F2 + f);
    const float x0 = bf2f(xb.x), x1 = bf2f(xb.y), x2 = bf2f(xb.z), x3 = bf2f(xb.w);
    float p;
    { float v = x0 + xr.x; v = v > 0.f ? v : 0.2f * v; p  = v * at.x; }
    { float v = x1 + xr.y; v = v > 0.f ? v : 0.2f * v; p += v * at.y; }
    { float v = x2 + xr.z; v = v > 0.f ? v : 0.2f * v; p += v * at.z; }
    { float v = x3 + xr.w; v = v > 0.f ? v : 0.2f * v; p += v * at.w; }
    p += __shfl_xor(p, 1);
    p += __shfl_xor(p, 2);
    p += __shfl_xor(p, 4);
    p += __shfl_xor(p, 8);
    p += __shfl_xor(p, 16);                   // per-head score, uniform in each half
    const float mn = fmaxf(m, p);
    const float sc = __expf(m - mn);          // first iter: exp(-huge) = 0
    const float w  = __expf(p - mn);
    dsum = dsum * sc + w;
    a0 = a0 * sc + w * x0; a1 = a1 * sc + w * x1;
    a2 = a2 * sc + w * x2; a3 = a3 * sc + w * x3;
    m = mn;
  }
  const float inv = 1.f / (dsum + 1e-16f);
  a0 *= inv; a1 *= inv; a2 *= inv; a3 *= inv;
  // mean over heads: lane l (head0) pairs with lane l+32 (head1)
  float o0 = 0.5f * (a0 + __shfl_xor(a0, 32));
  float o1 = 0.5f * (a1 + __shfl_xor(a1, 32));
  float o2 = 0.5f * (a2 + __shfl_xor(a2, 32));
  float o3 = 0.5f * (a3 + __shfl_xor(a3, 32));
  if (lane < 32) {
    float4 r;
    r.x = fmaxf(o0 + bias[f + 0], 0.f);
    r.y = fmaxf(o1 + bias[f + 1], 0.f);
    r.z = fmaxf(o2 + bias[f + 2], 0.f);
    r.w = fmaxf(o3 + bias[f + 3], 0.f);
    *(float4*)(OUT + (size_t)node * CH + f) = r;
  }
}

// ---------------- gate scalar: one wave per node ----------------
__global__ __launch_bounds__(256) void gate_dot(
    const float* __restrict__ T, const float* __restrict__ w2,
    const float* __restrict__ b2, float* __restrict__ gate, int N) {
  int node = (int)((blockIdx.x * (size_t)256 + threadIdx.x) >> 6);
  if (node >= N) return;
  const int lane = threadIdx.x & 63;
  const float* tr = T + (size_t)node * CH;
  float p = tr[lane] * w2[lane] + tr[lane + 64] * w2[lane + 64];
  p += __shfl_xor(p, 1);
  p += __shfl_xor(p, 2);
  p += __shfl_xor(p, 4);
  p += __shfl_xor(p, 8);
  p += __shfl_xor(p, 16);
  p += __shfl_xor(p, 32);
  if (lane == 0) gate[node] = p + b2[0];
}

// ---------------- pool phase A: per-graph max & denom ----------------
__global__ __launch_bounds__(256) void pool_stats(
    const float* __restrict__ gate, const int* __restrict__ batch,
    float* __restrict__ pm, float* __restrict__ pd, int N) {
  const int g = blockIdx.x, tid = threadIdx.x;
  int lo = 0, hi = N;
  while (lo < hi) { int mid = (lo + hi) >> 1; if (batch[mid] < g) lo = mid + 1; else hi = mid; }
  const int s = lo;
  lo = 0; hi = N;
  while (lo < hi) { int mid = (lo + hi) >> 1; if (batch[mid] < g + 1) lo = mid + 1; else hi = mid; }
  const int e = lo;
  __shared__ float red[256];
  float m = -3.4e38f;
  for (int n = s + tid; n < e; n += 256) m = fmaxf(m, gate[n]);
  red[tid] = m; __syncthreads();
  for (int off = 128; off; off >>= 1) {
    if (tid < off) red[tid] = fmaxf(red[tid], red[tid + off]);
    __syncthreads();
  }
  m = red[0]; __syncthreads();
  float d = 0.f;
  for (int n = s + tid; n < e; n += 256) d += expf(gate[n] - m);
  red[tid] = d; __syncthreads();
  for (int off = 128; off; off >>= 1) {
    if (tid < off) red[tid] += red[tid + off];
    __syncthreads();
  }
  if (tid == 0) { pm[g] = m; pd[g] = red[0]; }
}

// ---------------- pool phase B: deterministic partial sums ----------------
__global__ __launch_bounds__(128) void pool_partial(
    const float* __restrict__ gate, const int* __restrict__ batch,
    const float* __restrict__ pm, const float* __restrict__ pd,
    const float* __restrict__ H, float* __restrict__ PART, int N) {
  const int g = blockIdx.x / PS, j = blockIdx.x % PS;
  const int tid = threadIdx.x;
  int lo = 0, hi = N;
  while (lo < hi) { int mid = (lo + hi) >> 1; if (batch[mid] < g) lo = mid + 1; else hi = mid; }
  const int s = lo;
  lo = 0; hi = N;
  while (lo < hi) { int mid = (lo + hi) >> 1; if (batch[mid] < g + 1) lo = mid + 1; else hi = mid; }
  const int e = lo;
  const int len = e - s;
  const int per = (len + PS - 1) / PS;
  const int ns = s + j * per;
  const int ne = min(ns + per, e);
  const float m = pm[g];
  const float inv = 1.f / (pd[g] + 1e-16f);
  float acc = 0.f;
  for (int n = ns; n < ne; ++n) {
    const float w = expf(gate[n] - m);
    acc += w * H[(size_t)n * CH + tid];
  }
  PART[(size_t)blockIdx.x * CH + tid] = acc * inv;
}
__global__ __launch_bounds__(128) void pool_reduce(
    const float* __restrict__ PART, float* __restrict__ Gout) {
  const int g = blockIdx.x, tid = threadIdx.x;
  float acc = 0.f;
#pragma unroll
  for (int j = 0; j < PS; ++j) acc += PART[(size_t)(g * PS + j) * CH + tid];
  Gout[(size_t)g * CH + tid] = acc;
}

// ---------------- head MLP + normalize ----------------
__global__ __launch_bounds__(128) void head_kernel(
    const float* __restrict__ Gin, const float* __restrict__ w1, const float* __restrict__ b1,
    const float* __restrict__ w2, const float* __restrict__ b2, float* __restrict__ out) {
  const int g = blockIdx.x, tid = threadIdx.x;
  __shared__ float gs[128], ts[128], o[2];
  gs[tid] = Gin[(size_t)g * CH + tid];
  __syncthreads();
  float a = b1[tid];
  for (int k = 0; k < CH; ++k) a += w1[tid * CH + k] * gs[k];
  ts[tid] = fmaxf(a, 0.f);
  __syncthreads();
  if (tid < 2) {
    float v = b2[tid];
    for (int d2 = 0; d2 < CH; ++d2) v += w2[tid * CH + d2] * ts[d2];
    o[tid] = v;
  }
  __syncthreads();
  if (tid == 0) {
    float nrm = sqrtf(o[0] * o[0] + o[1] * o[1]);
    nrm = fmaxf(nrm, 1e-12f);
    out[g * 2 + 0] = o[0] / nrm;
    out[g * 2 + 1] = o[1] / nrm;
  }
}

extern "C" void kernel_launch(void* const* d_in, const int* in_sizes, int n_in,
                              void* d_out, int out_size, void* d_ws, size_t ws_size,
                              hipStream_t stream) {
  const float* x       = (const float*)d_in[0];
  const int*   ei      = (const int*)d_in[1];
  const int*   batch   = (const int*)d_in[2];
  const float* enc_w1  = (const float*)d_in[3];
  const float* enc_b1  = (const float*)d_in[4];
  const float* enc_w2  = (const float*)d_in[5];
  const float* enc_b2  = (const float*)d_in[6];
  const float* c1_wl   = (const float*)d_in[7];
  const float* c1_bl   = (const float*)d_in[8];
  const float* c1_wr   = (const float*)d_in[9];
  const float* c1_br   = (const float*)d_in[10];
  const float* c1_att  = (const float*)d_in[11];
  const float* c1_bias = (const float*)d_in[12];
  const float* c2_wl   = (const float*)d_in[13];
  const float* c2_bl   = (const float*)d_in[14];
  const float* c2_wr   = (const float*)d_in[15];
  const float* c2_br   = (const float*)d_in[16];
  const float* c2_att  = (const float*)d_in[17];
  const float* c2_bias = (const float*)d_in[18];
  const float* gate_w1 = (const float*)d_in[19];
  const float* gate_b1 = (const float*)d_in[20];
  const float* gate_w2 = (const float*)d_in[21];
  const float* gate_b2 = (const float*)d_in[22];
  const float* head_w1 = (const float*)d_in[23];
  const float* head_b1 = (const float*)d_in[24];
  const float* head_w2 = (const float*)d_in[25];
  const float* head_b2 = (const float*)d_in[26];

  const int N    = in_sizes[2];
  const int E    = in_sizes[1] / 2;
  const int INF_ = in_sizes[0] / N;   // input feature dim (256)
  const int Etot = E + N;

  char* wp = (char*)d_ws;
  auto alloc = [&](size_t bytes) -> void* {
    void* p = (void*)wp;
    wp += (bytes + 255) & ~(size_t)255;
    return p;
  };
  ushort* XLb    = (ushort*)alloc((size_t)N * F2 * 2);
  float*  XR     = (float*)alloc((size_t)N * F2 * 4);
  float*  H0     = (float*)alloc((size_t)N * CH * 4);
  float*  H1     = (float*)alloc((size_t)N * CH * 4);
  float*  TG     = (float*)alloc((size_t)N * CH * 4);
  int*    counts = (int*)alloc((size_t)N * 4);
  int*    indptr = (int*)alloc((size_t)(N + 1) * 4);
  int*    cur    = (int*)alloc((size_t)N * 4);
  int*    csr_src= (int*)alloc((size_t)Etot * 4);
  float*  gateb  = (float*)alloc((size_t)N * 4);
  float*  GS     = (float*)alloc((size_t)NG * CH * 4);
  float*  pm     = (float*)alloc((size_t)NG * 4);
  float*  pd     = (float*)alloc((size_t)NG * 4);
  float*  PART   = (float*)alloc((size_t)NG * PS * CH * 4);

  const dim3 blk(256);
  const int gM = (N + 127) / 128;

  // encoder
  gemm_nt_mfma<1,0><<<dim3(gM, CH / 64), blk, 0, stream>>>(x, enc_w1, enc_b1, H0, nullptr, N, CH, INF_);
  gemm_nt_mfma<1,0><<<dim3(gM, CH / 64), blk, 0, stream>>>(H0, enc_w2, enc_b2, H1, nullptr, N, CH, CH);

  // CSR by dst (shared by both convs)
  fill_zero_i32<<<(N + 255) / 256, blk, 0, stream>>>(counts, N);
  edge_hist<<<(Etot + 255) / 256, blk, 0, stream>>>(ei, E, Etot, counts);
  scan_excl<<<1, 1024, 0, stream>>>(counts, indptr, N);
  copy_i32<<<(N + 255) / 256, blk, 0, stream>>>(indptr, cur, N);
  edge_scatter<<<(Etot + 255) / 256, blk, 0, stream>>>(ei, E, Etot, cur, csr_src);

  // conv1: XL in bf16 (gathered), XR in f32 (sequential)
  gemm_nt_mfma<0,1><<<dim3(gM, F2 / 64), blk, 0, stream>>>(H1, c1_wl, c1_bl, nullptr, XLb, N, F2, CH);
  gemm_nt_mfma<0,0><<<dim3(gM, F2 / 64), blk, 0, stream>>>(H1, c1_wr, c1_br, XR, nullptr, N, F2, CH);
  fused_conv<<<(N + 3) / 4, blk, 0, stream>>>(indptr, csr_src, XLb, XR, c1_att, c1_bias, H0, N);

  // conv2
  gemm_nt_mfma<0,1><<<dim3(gM, F2 / 64), blk, 0, stream>>>(H0, c2_wl, c2_bl, nullptr, XLb, N, F2, CH);
  gemm_nt_mfma<0,0><<<dim3(gM, F2 / 64), blk, 0, stream>>>(H0, c2_wr, c2_br, XR, nullptr, N, F2, CH);
  fused_conv<<<(N + 3) / 4, blk, 0, stream>>>(indptr, csr_src, XLb, XR, c2_att, c2_bias, H1, N);

  // gate MLP -> scalar gate
  gemm_nt_mfma<1,0><<<dim3(gM, CH / 64), blk, 0, stream>>>(H1, gate_w1, gate_b1, TG, nullptr, N, CH, CH);
  gate_dot<<<(N + 3) / 4, blk, 0, stream>>>(TG, gate_w2, gate_b2, gateb, N);

  // pooling: stats -> deterministic partials -> reduce
  pool_stats<<<NG, blk, 0, stream>>>(gateb, batch, pm, pd, N);
  pool_partial<<<NG * PS, 128, 0, stream>>>(gateb, batch, pm, pd, H1, PART, N);
  pool_reduce<<<NG, 128, 0, stream>>>(PART, GS);

  // head + normalize
  head_kernel<<<NG, 128, 0, stream>>>(GS, head_w1, head_b1, head_w2, head_b2, (float*)d_out);
}